// Round 15
// baseline (1740.589 us; speedup 1.0000x reference)
//
#include <hip/hip_runtime.h>

// NeuralIF GraphNet: 3 layers x (lower GraphNet, upper GraphNet).
// Surviving structure (R14-R20): bucket+row counting sort -> u64 keys +
//   attrs + CSR row_offs; folded A-tables; CSR nodemlp; dual-segment prep.
// R19: nodew eliminated. 503.6us. R20: dual-segment prep. 489.9us BEST.
// R21 FAILED: hipLaunchCooperativeKernel version returned all-zero output
//      (absmax 6.9 = max|ref|) -> cooperative launch rejected under graph
//      capture; fused logic itself never executed.
// R23 (this round): same fusion via MANUAL grid barrier (device-scope
//      atomics + __threadfence sense barrier) in a REGULAR launch.
//      __launch_bounds__(256,4) guarantees 4 blk/CU -> 1024 co-resident;
//      occupancy query caps grid defensively. 12 barriers (~2-3us each)
//      replace ~80-100us of launch gaps across 12 dispatches.

typedef unsigned int u32;
typedef unsigned long long u64;

#define NB_SHIFT 8
#define NB_SIZE 256
#define RSTRIDE 1104  // per-GraphNet region: ebins[64] nbins[64*16] pad

__device__ __forceinline__ float wave_sum(float v) {
#pragma unroll
    for (int off = 32; off > 0; off >>= 1) v += __shfl_down(v, off, 64);
    return v;
}

// sense-reversing grid barrier: bar[0]=arrive count, bar[1]=generation
__device__ __forceinline__ void gbar(u32* __restrict__ bar) {
    __threadfence();
    __syncthreads();
    if (threadIdx.x == 0) {
        const u32 g0 = atomicAdd(&bar[1], 0u);
        if (atomicAdd(&bar[0], 1u) == gridDim.x - 1u) {
            atomicExch(&bar[0], 0u);
            __threadfence();
            atomicAdd(&bar[1], 1u);
        } else {
            while (atomicAdd(&bar[1], 0u) == g0) __builtin_amdgcn_s_sleep(8);
        }
    }
    __syncthreads();
    __threadfence();
}

// ---------------- bucketed-list build (once per call) ----------------

__global__ __launch_bounds__(512) void hist_kernel(
    const int* __restrict__ lr, const int* __restrict__ ur,
    u32* __restrict__ hist, int E, int B) {
    __shared__ u32 h[512];
    const int t = threadIdx.x;
    if (t < B) h[t] = 0;
    __syncthreads();
    const int s = blockIdx.y;
    const int* rows = s ? ur : lr;
    for (int i = blockIdx.x * 512 + t; i < E; i += gridDim.x * 512)
        atomicAdd(&h[rows[i] >> NB_SHIFT], 1u);
    __syncthreads();
    if (t < B && h[t]) atomicAdd(&hist[s * B + t], h[t]);
}

// parallel exclusive scan of both segments (B <= 512), one block
__global__ __launch_bounds__(512) void scan_kernel(
    const u32* __restrict__ hist, u32* __restrict__ offs,
    u32* __restrict__ cur, int B) {
    __shared__ u32 sh[512];
    const int t = threadIdx.x;
    for (int s = 0; s < 2; ++s) {
        const u32 v = (t < B) ? hist[s * B + t] : 0u;
        sh[t] = v;
        __syncthreads();
#pragma unroll
        for (int off = 1; off < 512; off <<= 1) {
            const u32 add = (t >= off) ? sh[t - off] : 0u;
            __syncthreads();
            sh[t] += add;
            __syncthreads();
        }
        const u32 exc = sh[t] - v;
        if (t < B) {
            offs[s * (B + 1) + t] = exc;
            cur[s * B + t] = exc;
        }
        if (t == 511) offs[s * (B + 1) + B] = sh[511];
        __syncthreads();
    }
}

// dual-segment scatter: packed bucket-permuted records {row, col, eid, attr}
#define SCHUNK 4096
__global__ __launch_bounds__(512) void scatter_kernel(
    const int* __restrict__ lr, const int* __restrict__ lc,
    const int* __restrict__ ur, const int* __restrict__ uc,
    const float* __restrict__ la, const float* __restrict__ ua,
    u32* __restrict__ cur, uint4* __restrict__ tmp, int E, int B) {
    __shared__ u32 lcnt[512], lbase[512];
    const int t = threadIdx.x;
    const int s = blockIdx.y;
    const int* rows = s ? ur : lr;
    const int* cols = s ? uc : lc;
    const float* attr = s ? ua : la;
    uint4* my = tmp + (size_t)s * E;
    if (t < B) lcnt[t] = 0;
    __syncthreads();
    const int base_e = blockIdx.x * SCHUNK;
#pragma unroll
    for (int k = 0; k < SCHUNK / 512; ++k) {
        const int e = base_e + k * 512 + t;
        if (e < E) atomicAdd(&lcnt[rows[e] >> NB_SHIFT], 1u);
    }
    __syncthreads();
    if (t < B) {
        const u32 c = lcnt[t];
        lbase[t] = c ? atomicAdd(&cur[s * B + t], c) : 0u;
        lcnt[t] = 0;
    }
    __syncthreads();
#pragma unroll
    for (int k = 0; k < SCHUNK / 512; ++k) {
        const int e = base_e + k * 512 + t;
        if (e < E) {
            const int r = rows[e];
            const int b = r >> NB_SHIFT;
            const u32 pos = lbase[b] + atomicAdd(&lcnt[b], 1u);
            my[pos] = make_uint4((u32)r, (u32)cols[e], (u32)e,
                                 __float_as_uint(attr[e]));
        }
    }
}

// ---- dual-segment per-bucket LDS counting sort: bucket -> row order ----

__global__ __launch_bounds__(512) void sort_kernel(
    const uint4* __restrict__ tmp, u64* __restrict__ ekeys,
    float* __restrict__ eattrs, const u32* __restrict__ offs,
    u32* __restrict__ row_offs, int E, int N, int B) {
    __shared__ u32 cnt[NB_SIZE];
    __shared__ u32 scn[NB_SIZE];
    const int t = threadIdx.x;
    const int s = blockIdx.y;
    const int b = blockIdx.x;
    const uint4* in = tmp + (size_t)s * E;
    u64* okey = ekeys + (size_t)s * E;
    float* oattr = eattrs + (size_t)s * E;
    u32* rofs = row_offs + (size_t)s * (N + 1);
    const u32 beg = offs[s * (B + 1) + b], end = offs[s * (B + 1) + b + 1];
    if (t < NB_SIZE) cnt[t] = 0;
    __syncthreads();
    for (u32 i = beg + t; i < end; i += 512)
        atomicAdd(&cnt[in[i].x & (NB_SIZE - 1)], 1u);
    __syncthreads();
    if (t < NB_SIZE) scn[t] = cnt[t];
    __syncthreads();
#pragma unroll
    for (int off = 1; off < NB_SIZE; off <<= 1) {
        u32 add = 0;
        if (t < NB_SIZE && t >= off) add = scn[t - off];
        __syncthreads();
        if (t < NB_SIZE) scn[t] += add;
        __syncthreads();
    }
    const int n0 = b << NB_SHIFT;
    if (t < NB_SIZE) {
        const u32 excl = scn[t] - cnt[t];
        if (n0 + t < N) rofs[n0 + t] = beg + excl;
        cnt[t] = excl;  // reuse as write cursor
    }
    if (b == 0 && t == 0) rofs[N] = (u32)E;
    __syncthreads();
    for (u32 i = beg + t; i < end; i += 512) {
        const uint4 r = in[i];
        const u32 pos = beg + atomicAdd(&cnt[r.x & (NB_SIZE - 1)], 1u);
        okey[pos] = ((u64)r.z << 34) | ((u64)(r.x & 0x1FFFFu) << 17) |
                    (u64)(r.y & 0x1FFFFu);
        oattr[pos] = __uint_as_float(r.w);
    }
}

// --------------- persistent mega-kernel: atabx + 6x(edge[,node]) ----------
// Phase bodies identical to R20's atabx/edge/nodemlp kernels; gbar()
// replaces kernel boundaries. Flags are per-j wave-uniform runtime bools.

__global__ __launch_bounds__(256, 4) void fused_kernel(
    const u64* __restrict__ ekeys, const float* __restrict__ eattrs,
    float* __restrict__ AtabL, float* __restrict__ AtabU,
    const float4* __restrict__ xF, float* __restrict__ l_e,
    float* __restrict__ u_e, float* __restrict__ l_n,
    const float* __restrict__ eW1, const float* __restrict__ eb1,
    const float* __restrict__ eW2, const float* __restrict__ eb2,
    const float* __restrict__ nW1, const float* __restrict__ nb1,
    const float* __restrict__ nW2, const float* __restrict__ nb2,
    const float* __restrict__ gW1, const float* __restrict__ gb1,
    const float* __restrict__ gW2, const float* __restrict__ gb2,
    float* __restrict__ gslot, float* __restrict__ dyn_all,
    u32* __restrict__ bar, const u32* __restrict__ row_offs,
    float* __restrict__ outL, float* __restrict__ outU, int E, int N,
    float inv_E, int EG, int cpx, int NG, int cpn, int ng) {
    const int t = threadIdx.x;
    const int nblk = (int)gridDim.x;
    __shared__ float gsh[8];
    __shared__ float biasE[32];
    __shared__ float wpart[4];
    __shared__ float biasN[32];
    __shared__ float npart[4][8];

    // ---- phase A: the 3 lower A-tables from static x ----
    for (int vb = blockIdx.x; vb < ng; vb += nblk) {
        const int n = vb * 256 + t;
        if (n >= N) continue;
        const float4 x0 = xF[2 * (size_t)n], x1 = xF[2 * (size_t)n + 1];
        const float xs[8] = {x0.x, x0.y, x0.z, x0.w,
                             x1.x, x1.y, x1.z, x1.w};
        for (int m = 0; m < 3; ++m) {
            const float* __restrict__ WA = eW1 + (size_t)m * 832 + 8 * 32;
            float a[32];
#pragma unroll
            for (int j = 0; j < 32; ++j) a[j] = 0.0f;
#pragma unroll
            for (int k = 0; k < 8; ++k) {
                const float v = xs[k];
#pragma unroll
                for (int j = 0; j < 32; ++j)
                    a[j] = fmaf(v, WA[k * 32 + j], a[j]);
            }
            float4* An =
                (float4*)AtabL + (size_t)m * 8 * N + 8 * (size_t)n;
#pragma unroll
            for (int q = 0; q < 8; ++q)
                An[q] = make_float4(a[4 * q], a[4 * q + 1], a[4 * q + 2],
                                    a[4 * q + 3]);
        }
    }
    gbar(bar);

    const int wsl[6] = {0, 3, 1, 4, 2, 5};
    for (int j = 0; j < 6; ++j) {
        const bool lower = !(j & 1);
        const bool SKIP = (j == 2) || (j == 4);
        const bool FIRST = (j <= 1);
        const bool GAGG = (j < 5);
        const bool VALS = (j >= 4);
        const bool STORE = (j < 5);
        const bool GCOMP = (j >= 1);
        const int sl = wsl[j];
        const int psl = (j >= 1) ? wsl[j - 1] : 0;
        const float* __restrict__ W1 = eW1 + (size_t)sl * 832;
        const float* __restrict__ b1v = eb1 + (size_t)sl * 32;
        const float* __restrict__ W2 = eW2 + (size_t)sl * 32;
        const float* __restrict__ b2v = eb2 + sl;
        float* ebins = dyn_all + (size_t)j * RSTRIDE;  // j=5 region unused
        const float* pe =
            (j >= 1) ? dyn_all + (size_t)(j - 1) * RSTRIDE : nullptr;
        const float* pn = (j >= 1) ? pe + 64 : nullptr;
        const float* gprev = gslot + (size_t)(j >= 1 ? j - 1 : 0) * 8;
        float* gout = gslot + (size_t)j * 8;
        const u64* __restrict__ ekey = ekeys + (size_t)(lower ? 0 : 1) * E;
        const float* __restrict__ eattr =
            eattrs + (size_t)(lower ? 0 : 1) * E;
        const float4* __restrict__ Atab =
            (const float4*)(lower ? AtabL + (size_t)(j >> 1) * 32 * N
                                  : AtabU);
        const float4* __restrict__ xf =
            lower ? xF : (const float4*)l_n;
        const float* __restrict__ eprev = lower ? l_e : u_e;
        float* __restrict__ e_out = lower ? l_e : u_e;
        float* __restrict__ vals_out = (j == 4) ? outL : outU;
        const float* gW1j = gW1 + (size_t)psl * 544;
        const float* gb1j = gb1 + (size_t)psl * 32;
        const float* gW2j = gW2 + (size_t)psl * 256;
        const float* gb2j = gb2 + (size_t)psl * 8;

        // ---- per-j: g (wave 0) + biasE fold (once per block) ----
        if (GCOMP) {
            if (t < 64) {
                float nb[8];
#pragma unroll
                for (int q = 0; q < 8; ++q) nb[q] = pn[t * 16 + q];
                const float eb = pe[t];
                float gin[17];
#pragma unroll
                for (int q = 0; q < 8; ++q) {
                    const float s = wave_sum(nb[q]);
                    gin[q] = __shfl(s, 0, 64) / (float)N;
                }
                const float es = wave_sum(eb);
                gin[8] = __shfl(es, 0, 64) * inv_E;
#pragma unroll
                for (int k = 0; k < 8; ++k) gin[9 + k] = gprev[k];
                float hv = 0.0f;
                if (t < 32) {
                    hv = gb1j[t];
#pragma unroll
                    for (int k = 0; k < 17; ++k)
                        hv = fmaf(gin[k], gW1j[k * 32 + t], hv);
                    hv = fmaxf(hv, 0.0f);
                }
#pragma unroll
                for (int q = 0; q < 8; ++q) {
                    const float c = (t < 32) ? hv * gW2j[t * 8 + q] : 0.0f;
                    const float s = wave_sum(c);
                    if (t == 0) {
                        const float gv = gb2j[q] + s;
                        gsh[q] = gv;
                        if (blockIdx.x == 0) gout[q] = gv;
                    }
                }
            }
        } else {
            if (t < 8) gsh[t] = gprev[t];  // zeros for GraphNet 0
        }
        __syncthreads();
        if (t < 32) {
            float v = b1v[t];
#pragma unroll
            for (int k = 0; k < 8; ++k) v = fmaf(gsh[k], W1[k * 32 + t], v);
            biasE[t] = v;
        }
        __syncthreads();

        // ---- edge phase: grid-stride over EG virtual blocks ----
        for (int vb = blockIdx.x; vb < EG; vb += nblk) {
            const int lid = (vb & 7) * cpx + (vb >> 3);
            const int i0 = lid * 256;
            if (i0 >= E) continue;  // block-uniform
            const int i = i0 + t;
            const bool valid = i < E;
            const int idx = valid ? i : i0;
            const u64 key = ekey[idx];
            const u32 c = (u32)key & 0x1FFFFu;
            const u32 r = (u32)(key >> 17) & 0x1FFFFu;
            float attr = 0.0f;
            if (FIRST || SKIP) attr = eattr[idx];
            float epv;
            if (FIRST) epv = attr;
            else epv = eprev[idx];
            const float4* __restrict__ Ar = Atab + 8 * (size_t)r;
            float h[32];
#pragma unroll
            for (int q = 0; q < 8; ++q) {
                const float4 av = Ar[q];
                const float4 bi = reinterpret_cast<const float4*>(biasE)[q];
                h[4 * q + 0] = bi.x + av.x; h[4 * q + 1] = bi.y + av.y;
                h[4 * q + 2] = bi.z + av.z; h[4 * q + 3] = bi.w + av.w;
            }
            const float4 xc0 = xf[2 * (size_t)c];
            const float4 xc1 = xf[2 * (size_t)c + 1];
            const float cx[8] = {xc0.x, xc0.y, xc0.z, xc0.w,
                                 xc1.x, xc1.y, xc1.z, xc1.w};
            const float* __restrict__ Wc = W1 + 16 * 32;
#pragma unroll
            for (int k = 0; k < 8; ++k) {
                const float v = cx[k];
#pragma unroll
                for (int jj = 0; jj < 32; ++jj)
                    h[jj] = fmaf(v, Wc[k * 32 + jj], h[jj]);
            }
            const float* __restrict__ W24 = W1 + 24 * 32;
#pragma unroll
            for (int jj = 0; jj < 32; ++jj)
                h[jj] = fmaf(epv, W24[jj], h[jj]);
            if (SKIP) {
                const float* __restrict__ W25 = W1 + 25 * 32;
#pragma unroll
                for (int jj = 0; jj < 32; ++jj)
                    h[jj] = fmaf(attr, W25[jj], h[jj]);
            }
            float out = b2v[0];
#pragma unroll
            for (int jj = 0; jj < 32; ++jj)
                out = fmaf(fmaxf(h[jj], 0.0f), W2[jj], out);
            if (valid) {
                if (STORE) e_out[i] = out;
                if (VALS) {
                    const u32 eid = (u32)(key >> 34);
                    vals_out[eid] = (r == c) ? expf(out) : out;
                }
            }
            if (GAGG) {
                const float s = wave_sum(valid ? out : 0.0f);
                if ((t & 63) == 0) wpart[t >> 6] = s;
                __syncthreads();
                if (t == 0)
                    atomicAdd(&ebins[lid & 63],
                              wpart[0] + wpart[1] + wpart[2] + wpart[3]);
                __syncthreads();  // guard wpart reuse next iteration
            }
        }
        gbar(bar);
        if (j == 5) break;

        // ---- node phase j (EVEN = lower): CSR sum + MLP (+AtabU fuse) ----
        const bool EVEN = lower;
        const float* __restrict__ nW1j = nW1 + (size_t)sl * 544;
        const float* __restrict__ nb1j = nb1 + (size_t)sl * 32;
        const float* __restrict__ nW2j = nW2 + (size_t)sl * 256;
        const float* __restrict__ nb2j = nb2 + (size_t)sl * 8;
        const float* gj = gslot + (size_t)j * 8;
        float* nbins = ebins + 64;
        const u32* __restrict__ roffs =
            row_offs + (size_t)(lower ? 0 : 1) * (N + 1);
        const float* __restrict__ W1u = eW1 + (size_t)wsl[j + 1] * 832;
        if (t < 32) {
            float v = nb1j[t];
#pragma unroll
            for (int k = 0; k < 8; ++k) v = fmaf(gj[k], nW1j[k * 32 + t], v);
            biasN[t] = v;
        }
        __syncthreads();
        for (int vb = blockIdx.x; vb < NG; vb += nblk) {
            const int lid = (vb & 7) * cpn + (vb >> 3);
            const int n = lid * 256 + t;
            const bool active = n < N;
            const int idx = active ? n : (N - 1);
            const u32 beg = roffs[idx], end = roffs[idx + 1];
            float ssum = 0.0f;
            for (u32 i2 = beg; i2 < end; ++i2) ssum += e_out[i2];
            const float agg = ssum / fmaxf((float)(end - beg), 1.0f);
            const float4 x0 = xf[2 * (size_t)idx];
            const float4 x1 = xf[2 * (size_t)idx + 1];
            float in[9] = {x0.x, x0.y, x0.z, x0.w,
                           x1.x, x1.y, x1.z, x1.w, agg};
            float h[32];
#pragma unroll
            for (int jj = 0; jj < 8; ++jj) {
                const float4 bb = reinterpret_cast<const float4*>(biasN)[jj];
                h[4 * jj + 0] = bb.x; h[4 * jj + 1] = bb.y;
                h[4 * jj + 2] = bb.z; h[4 * jj + 3] = bb.w;
            }
            const float* __restrict__ Wk = nW1j + 8 * 32;
#pragma unroll
            for (int k = 0; k < 9; ++k) {
                const float v = in[k];
#pragma unroll
                for (int jj = 0; jj < 32; ++jj)
                    h[jj] = fmaf(v, Wk[k * 32 + jj], h[jj]);
            }
            float o[8];
#pragma unroll
            for (int q = 0; q < 8; ++q) o[q] = nb2j[q];
#pragma unroll
            for (int jj = 0; jj < 32; ++jj) {
                const float hv = fmaxf(h[jj], 0.0f);
#pragma unroll
                for (int q = 0; q < 8; ++q)
                    o[q] = fmaf(hv, nW2j[jj * 8 + q], o[q]);
            }
            if (EVEN && active) {
                reinterpret_cast<float4*>(l_n)[2 * n] =
                    make_float4(o[0], o[1], o[2], o[3]);
                reinterpret_cast<float4*>(l_n)[2 * n + 1] =
                    make_float4(o[4], o[5], o[6], o[7]);
                const float* __restrict__ WA = W1u + 8 * 32;
                float a[32];
#pragma unroll
                for (int jj = 0; jj < 32; ++jj) a[jj] = 0.0f;
#pragma unroll
                for (int k = 0; k < 8; ++k) {
                    const float v = o[k];
#pragma unroll
                    for (int jj = 0; jj < 32; ++jj)
                        a[jj] = fmaf(v, WA[k * 32 + jj], a[jj]);
                }
                float4* An = (float4*)AtabU + 8 * (size_t)n;
#pragma unroll
                for (int q = 0; q < 8; ++q)
                    An[q] = make_float4(a[4 * q], a[4 * q + 1],
                                        a[4 * q + 2], a[4 * q + 3]);
            }
#pragma unroll
            for (int q = 0; q < 8; ++q) {
                const float s2 = wave_sum(active ? o[q] : 0.0f);
                if ((t & 63) == 0) npart[t >> 6][q] = s2;
            }
            __syncthreads();
            if (t < 8) {
                float a = 0.0f;
#pragma unroll
                for (int w = 0; w < 4; ++w) a += npart[w][t];
                atomicAdd(&nbins[(vb & 63) * 16 + t], a);
            }
            __syncthreads();  // guard npart reuse next iteration
        }
        gbar(bar);
    }
}

extern "C" void kernel_launch(void* const* d_in, const int* in_sizes, int n_in,
                              void* d_out, int out_size, void* d_ws,
                              size_t ws_size, hipStream_t stream) {
    const float* x = (const float*)d_in[0];
    const int* l_ei = (const int*)d_in[1];
    const int* u_ei = (const int*)d_in[2];
    const float* l_attr = (const float*)d_in[3];
    const float* u_attr = (const float*)d_in[4];
    const float* eW1 = (const float*)d_in[5];
    const float* eb1 = (const float*)d_in[6];
    const float* eW2 = (const float*)d_in[7];
    const float* eb2 = (const float*)d_in[8];
    const float* nW1 = (const float*)d_in[9];
    const float* nb1 = (const float*)d_in[10];
    const float* nW2 = (const float*)d_in[11];
    const float* nb2 = (const float*)d_in[12];
    const float* gW1 = (const float*)d_in[13];
    const float* gb1 = (const float*)d_in[14];
    const float* gW2 = (const float*)d_in[15];
    const float* gb2 = (const float*)d_in[16];

    const int E = in_sizes[3];      // 1,100,000
    const int N = in_sizes[0] / 8;  // 100,000
    const int B = (N + NB_SIZE - 1) >> NB_SHIFT;  // 391 buckets
    const int Ep = (E + 3) & ~3;    // float4-safe stride for emb arrays

    // workspace layout (~101MB, ws = 256MB):
    //  [ekeys 2E u64][eattrs 2E f32]
    //  [tmp 2E uint4 (dead after sort) -> AtabU 32N + l_e + u_e + l_n]
    //  [AtabL 96N][gslot|hist|dyn(6)|bar|offs|cur|row_offs]
    u64* ekeys = (u64*)d_ws;                       // 2E keys
    float* eattrs = (float*)(ekeys + (size_t)2 * E);  // 2E attrs
    uint4* tmp = (uint4*)(eattrs + (size_t)2 * E); // 2E tmp records
    float* AtabU = (float*)tmp;                    // 32N (alias, post-sort)
    float* l_e = AtabU + (size_t)32 * N;           // Ep (alias)
    float* u_e = l_e + Ep;                         // Ep (alias)
    float* l_n = u_e + Ep;                         // 8N (alias; fits in tmp)
    float* AtabL = (float*)(tmp + (size_t)2 * E);  // 96N (3 lower tables)
    float* gslot = AtabL + (size_t)96 * N;         // 7 x 8
    u32* hist = (u32*)(gslot + 56);                // 2B
    float* dyn_all = (float*)(hist + 2 * B);       // 6 * RSTRIDE
    u32* bar = (u32*)(dyn_all + 6 * RSTRIDE);      // 8 (cnt, gen, pad)
    u32* offs = bar + 8;                           // 2(B+1)
    u32* cur = offs + 2 * (B + 1);                 // 2B
    u32* row_offs = cur + 2 * B;                   // 2(N+1) CSR offsets

    const int* lr = l_ei;
    const int* lc = l_ei + E;
    const int* ur = u_ei;
    const int* uc = u_ei + E;
    const int sg = (E + SCHUNK - 1) / SCHUNK;
    const int ng = (N + 255) / 256;
    const int ngp = (ng + 7) & ~7;   // padded node grid (%8) for XCD swizzle
    const int cpn = ngp >> 3;
    const int eg = (E + 255) / 256;
    const int nwg8 = (eg + 7) & ~7;  // padded edge grid (%8)
    const int cpx = nwg8 >> 3;
    const float invE = 1.0f / (float)E;
    float* outL = (float*)d_out;
    float* outU = outL + E;

    // one memset: gslots + hist + 6 bin regions + barrier words
    hipMemsetAsync(gslot, 0,
                   (size_t)(56 + 2 * B + 6 * RSTRIDE + 8) * sizeof(float),
                   stream);
    hist_kernel<<<dim3(64, 2), 512, 0, stream>>>(lr, ur, hist, E, B);
    scan_kernel<<<1, 512, 0, stream>>>(hist, offs, cur, B);
    scatter_kernel<<<dim3(sg, 2), 512, 0, stream>>>(lr, lc, ur, uc, l_attr,
                                                    u_attr, cur, tmp, E, B);
    sort_kernel<<<dim3(B, 2), 512, 0, stream>>>(tmp, ekeys, eattrs, offs,
                                                row_offs, E, N, B);

    // persistent mega-kernel: grid capped to guaranteed co-residency
    int maxPerCU = 0;
    int nblk = 1024;
    if (hipOccupancyMaxActiveBlocksPerMultiprocessor(
            &maxPerCU, (const void*)fused_kernel, 256, 0) == hipSuccess &&
        maxPerCU >= 1) {
        const int cap = maxPerCU * 256;  // 256 CUs on MI355X
        if (cap < nblk) nblk = cap;
    }
    fused_kernel<<<nblk, 256, 0, stream>>>(
        ekeys, eattrs, AtabL, AtabU, (const float4*)x, l_e, u_e, l_n, eW1,
        eb1, eW2, eb2, nW1, nb1, nW2, nb2, gW1, gb1, gW2, gb2, gslot,
        dyn_all, bar, row_offs, outL, outU, E, N, invE, nwg8, cpx, ngp, cpn,
        ng);
}

// Round 16
// 512.099 us; speedup vs baseline: 3.3989x; 3.3989x over previous
//
#include <hip/hip_runtime.h>

// NeuralIF GraphNet: 3 layers x (lower GraphNet, upper GraphNet).
// Surviving structure (R14-R20): bucket+row counting sort -> u64 keys +
//   attrs + CSR row_offs; folded A-tables; CSR nodemlp; dual-segment prep.
// R19: nodew eliminated. 503.6us. R20: dual-segment prep. 489.9us BEST.
// R21 FAILED: hipLaunchCooperativeKernel rejected under graph capture
//      (all-zero output).
// R23 FAILED-SLOW (1740us): manual sense-reversing grid barrier costs
//      ~100us per barrier (1024 block-leaders RMW-spinning one cacheline
//      across 8 non-coherent L2s) >> the ~6us launch gap it replaces.
//      CONCLUSION: kernel-boundary < device-barrier on this platform;
//      grid-wide fusion abandoned for good.
// R24 (this round): R20 verbatim + one block-local dispatch elimination:
//      atabx folded into sort_kernel (bucket b, segment 0 block owns nodes
//      [256b,256b+256) -> threads t<256 compute the 3 lower A-tables after
//      the scatter pass; no overlap with sort's own arrays, no new sync).
//      Deletes 1 dispatch + 1 launch gap; A-table FMAs hide under sort's
//      latency-bound scatter.

typedef unsigned int u32;
typedef unsigned long long u64;

#define NB_SHIFT 8
#define NB_SIZE 256
#define RSTRIDE 1104  // per-GraphNet region: ebins[64] nbins[64*16] pad

__device__ __forceinline__ float wave_sum(float v) {
#pragma unroll
    for (int off = 32; off > 0; off >>= 1) v += __shfl_down(v, off, 64);
    return v;
}

// ---------------- bucketed-list build (once per call) ----------------

__global__ __launch_bounds__(512) void hist_kernel(
    const int* __restrict__ lr, const int* __restrict__ ur,
    u32* __restrict__ hist, int E, int B) {
    __shared__ u32 h[512];
    const int t = threadIdx.x;
    if (t < B) h[t] = 0;
    __syncthreads();
    const int s = blockIdx.y;
    const int* rows = s ? ur : lr;
    for (int i = blockIdx.x * 512 + t; i < E; i += gridDim.x * 512)
        atomicAdd(&h[rows[i] >> NB_SHIFT], 1u);
    __syncthreads();
    if (t < B && h[t]) atomicAdd(&hist[s * B + t], h[t]);
}

// parallel exclusive scan of both segments (B <= 512), one block
__global__ __launch_bounds__(512) void scan_kernel(
    const u32* __restrict__ hist, u32* __restrict__ offs,
    u32* __restrict__ cur, int B) {
    __shared__ u32 sh[512];
    const int t = threadIdx.x;
    for (int s = 0; s < 2; ++s) {
        const u32 v = (t < B) ? hist[s * B + t] : 0u;
        sh[t] = v;
        __syncthreads();
#pragma unroll
        for (int off = 1; off < 512; off <<= 1) {
            const u32 add = (t >= off) ? sh[t - off] : 0u;
            __syncthreads();
            sh[t] += add;
            __syncthreads();
        }
        const u32 exc = sh[t] - v;
        if (t < B) {
            offs[s * (B + 1) + t] = exc;
            cur[s * B + t] = exc;
        }
        if (t == 511) offs[s * (B + 1) + B] = sh[511];
        __syncthreads();
    }
}

// dual-segment scatter: packed bucket-permuted records {row, col, eid, attr}
#define SCHUNK 4096
__global__ __launch_bounds__(512) void scatter_kernel(
    const int* __restrict__ lr, const int* __restrict__ lc,
    const int* __restrict__ ur, const int* __restrict__ uc,
    const float* __restrict__ la, const float* __restrict__ ua,
    u32* __restrict__ cur, uint4* __restrict__ tmp, int E, int B) {
    __shared__ u32 lcnt[512], lbase[512];
    const int t = threadIdx.x;
    const int s = blockIdx.y;
    const int* rows = s ? ur : lr;
    const int* cols = s ? uc : lc;
    const float* attr = s ? ua : la;
    uint4* my = tmp + (size_t)s * E;
    if (t < B) lcnt[t] = 0;
    __syncthreads();
    const int base_e = blockIdx.x * SCHUNK;
#pragma unroll
    for (int k = 0; k < SCHUNK / 512; ++k) {
        const int e = base_e + k * 512 + t;
        if (e < E) atomicAdd(&lcnt[rows[e] >> NB_SHIFT], 1u);
    }
    __syncthreads();
    if (t < B) {
        const u32 c = lcnt[t];
        lbase[t] = c ? atomicAdd(&cur[s * B + t], c) : 0u;
        lcnt[t] = 0;
    }
    __syncthreads();
#pragma unroll
    for (int k = 0; k < SCHUNK / 512; ++k) {
        const int e = base_e + k * 512 + t;
        if (e < E) {
            const int r = rows[e];
            const int b = r >> NB_SHIFT;
            const u32 pos = lbase[b] + atomicAdd(&lcnt[b], 1u);
            my[pos] = make_uint4((u32)r, (u32)cols[e], (u32)e,
                                 __float_as_uint(attr[e]));
        }
    }
}

// ---- dual-segment per-bucket LDS counting sort: bucket -> row order ----
// Emits split arrays: u64 key {eid:21|row:17|col:17} + float attr + CSR
// row_offs. Segment-0 blocks ALSO compute the bucket's 3 lower A-tables
// (fused atabx: reads x, writes AtabL; disjoint from sort arrays).

__global__ __launch_bounds__(512) void sort_kernel(
    const uint4* __restrict__ tmp, u64* __restrict__ ekeys,
    float* __restrict__ eattrs, const u32* __restrict__ offs,
    u32* __restrict__ row_offs, const float4* __restrict__ xf,
    const float* __restrict__ eW1, float4* __restrict__ AtabL,
    int E, int N, int B) {
    __shared__ u32 cnt[NB_SIZE];
    __shared__ u32 scn[NB_SIZE];
    const int t = threadIdx.x;
    const int s = blockIdx.y;
    const int b = blockIdx.x;
    const uint4* in = tmp + (size_t)s * E;
    u64* okey = ekeys + (size_t)s * E;
    float* oattr = eattrs + (size_t)s * E;
    u32* rofs = row_offs + (size_t)s * (N + 1);
    const u32 beg = offs[s * (B + 1) + b], end = offs[s * (B + 1) + b + 1];
    if (t < NB_SIZE) cnt[t] = 0;
    __syncthreads();
    for (u32 i = beg + t; i < end; i += 512)
        atomicAdd(&cnt[in[i].x & (NB_SIZE - 1)], 1u);
    __syncthreads();
    if (t < NB_SIZE) scn[t] = cnt[t];
    __syncthreads();
#pragma unroll
    for (int off = 1; off < NB_SIZE; off <<= 1) {
        u32 add = 0;
        if (t < NB_SIZE && t >= off) add = scn[t - off];
        __syncthreads();
        if (t < NB_SIZE) scn[t] += add;
        __syncthreads();
    }
    const int n0 = b << NB_SHIFT;
    if (t < NB_SIZE) {
        const u32 excl = scn[t] - cnt[t];
        if (n0 + t < N) rofs[n0 + t] = beg + excl;
        cnt[t] = excl;  // reuse as write cursor
    }
    if (b == 0 && t == 0) rofs[N] = (u32)E;
    __syncthreads();
    for (u32 i = beg + t; i < end; i += 512) {
        const uint4 r = in[i];
        const u32 pos = beg + atomicAdd(&cnt[r.x & (NB_SIZE - 1)], 1u);
        okey[pos] = ((u64)r.z << 34) | ((u64)(r.x & 0x1FFFFu) << 17) |
                    (u64)(r.y & 0x1FFFFu);
        oattr[pos] = __uint_as_float(r.w);
    }
    // ---- fused atabx (segment 0 only): 3 lower A-tables for this bucket ----
    if (s == 0 && t < NB_SIZE) {
        const int n = n0 + t;
        if (n < N) {
            const float4 x0 = xf[2 * (size_t)n], x1 = xf[2 * (size_t)n + 1];
            const float xs[8] = {x0.x, x0.y, x0.z, x0.w,
                                 x1.x, x1.y, x1.z, x1.w};
            for (int m = 0; m < 3; ++m) {
                const float* __restrict__ WA =
                    eW1 + (size_t)m * 832 + 8 * 32;
                float a[32];
#pragma unroll
                for (int j = 0; j < 32; ++j) a[j] = 0.0f;
#pragma unroll
                for (int k = 0; k < 8; ++k) {
                    const float v = xs[k];
#pragma unroll
                    for (int j = 0; j < 32; ++j)
                        a[j] = fmaf(v, WA[k * 32 + j], a[j]);
                }
                float4* An = AtabL + (size_t)m * 8 * N + 8 * (size_t)n;
#pragma unroll
                for (int q = 0; q < 8; ++q)
                    An[q] = make_float4(a[4 * q], a[4 * q + 1],
                                        a[4 * q + 2], a[4 * q + 3]);
            }
        }
    }
}

// ---------------- edge MLP: flat grid, one edge per thread ----------------
// GCOMP (wave 0) computes g inline from prev bins; t<32 folds b1 + g.W1[0:8]
// into LDS biasE. Atab rows carry only x.W1[8:16]. Row-sorted order keeps
// A-row gathers L1-broadcast; XCD-chunked swizzle.

template <bool SKIP, bool FIRST, bool GAGG, bool VALS, bool STORE, bool GCOMP>
__global__ __launch_bounds__(256) void edge_kernel(
    const u64* __restrict__ ekey,      // packed row-sorted keys
    const float* __restrict__ eattr,   // permuted original attrs
    const float4* __restrict__ Atab,   // per-node x.W1[8:16] partials
    const float4* __restrict__ xf,     // current node features (x or l_n)
    const float* __restrict__ eprev,   // prev edge emb (permuted), !FIRST
    const float* __restrict__ W1,      // 26x32 slice (row-major k,j)
    const float* __restrict__ b1,      // 32
    const float* __restrict__ W2,      // 32
    const float* __restrict__ b2,      // 1
    const float* __restrict__ gprev,   // gslot[j-1] (or gslot[0]=0)
    float* __restrict__ gout,          // gslot[j] (GCOMP: block0 writes)
    const float* __restrict__ pebins,  // prev region e-mean bins (GCOMP)
    const float* __restrict__ pnbins,  // prev region n-mean bins (GCOMP)
    const float* __restrict__ gW1, const float* __restrict__ gb1,
    const float* __restrict__ gW2, const float* __restrict__ gb2,
    float* __restrict__ ebins,         // this region's e-mean bins (GAGG)
    float* __restrict__ e_out,         // edge emb store (permuted, STORE)
    float* __restrict__ vals_out,      // final output segment (VALS)
    int E, int N, float inv_E, int cpx) {
    __shared__ float gsh[8];
    __shared__ float biasE[32];
    __shared__ float wpart[4];
    const int t = threadIdx.x;
    const int lid = (blockIdx.x & 7) * cpx + (blockIdx.x >> 3);
    const int i0 = lid * 256;
    if (i0 >= E) return;  // padded-grid tail block (uniform exit)

    if constexpr (GCOMP) {
        if (t < 64) {  // wave 0: g = gMLP(n_mean, e_mean, g_prev)
            float nb[8];
#pragma unroll
            for (int q = 0; q < 8; ++q) nb[q] = pnbins[t * 16 + q];
            const float eb = pebins[t];
            float gin[17];
#pragma unroll
            for (int q = 0; q < 8; ++q) {
                const float s = wave_sum(nb[q]);
                gin[q] = __shfl(s, 0, 64) / (float)N;
            }
            const float es = wave_sum(eb);
            gin[8] = __shfl(es, 0, 64) * inv_E;
#pragma unroll
            for (int k = 0; k < 8; ++k) gin[9 + k] = gprev[k];
            float hv = 0.0f;
            if (t < 32) {
                hv = gb1[t];
#pragma unroll
                for (int k = 0; k < 17; ++k)
                    hv = fmaf(gin[k], gW1[k * 32 + t], hv);
                hv = fmaxf(hv, 0.0f);
            }
#pragma unroll
            for (int q = 0; q < 8; ++q) {
                const float c = (t < 32) ? hv * gW2[t * 8 + q] : 0.0f;
                const float s = wave_sum(c);
                if (t == 0) {
                    const float gv = gb2[q] + s;
                    gsh[q] = gv;
                    if (blockIdx.x == 0) gout[q] = gv;
                }
            }
        }
    } else {
        if (t < 8) gsh[t] = gprev[t];  // zeros for GraphNet 0
    }
    __syncthreads();
    if (t < 32) {  // fold uniform global contribution + b1 into bias
        float v = b1[t];
#pragma unroll
        for (int k = 0; k < 8; ++k) v = fmaf(gsh[k], W1[k * 32 + t], v);
        biasE[t] = v;
    }
    __syncthreads();

    const int i = i0 + t;
    const bool valid = i < E;
    const int idx = valid ? i : i0;

    const u64 key = ekey[idx];
    const u32 c = (u32)key & 0x1FFFFu;
    const u32 r = (u32)(key >> 17) & 0x1FFFFu;
    float attr = 0.0f;
    if constexpr (FIRST || SKIP) attr = eattr[idx];
    float epv;
    if constexpr (FIRST) epv = attr;
    else epv = eprev[idx];
    // A-row gather (8x16B; consecutive lanes share rows -> broadcast)
    const float4* __restrict__ Ar = Atab + 8 * (size_t)r;
    float h[32];
#pragma unroll
    for (int q = 0; q < 8; ++q) {
        const float4 av = Ar[q];
        const float4 bi = reinterpret_cast<const float4*>(biasE)[q];
        h[4 * q + 0] = bi.x + av.x; h[4 * q + 1] = bi.y + av.y;
        h[4 * q + 2] = bi.z + av.z; h[4 * q + 3] = bi.w + av.w;
    }
    // col features (32B gather, L2-resident table)
    const float4 xc0 = xf[2 * (size_t)c], xc1 = xf[2 * (size_t)c + 1];
    const float cx[8] = {xc0.x, xc0.y, xc0.z, xc0.w,
                         xc1.x, xc1.y, xc1.z, xc1.w};
    const float* __restrict__ Wc = W1 + 16 * 32;  // col rows 16..23
#pragma unroll
    for (int k = 0; k < 8; ++k) {
        const float v = cx[k];
#pragma unroll
        for (int j = 0; j < 32; ++j) h[j] = fmaf(v, Wc[k * 32 + j], h[j]);
    }
    const float* __restrict__ W24 = W1 + 24 * 32;
#pragma unroll
    for (int j = 0; j < 32; ++j) h[j] = fmaf(epv, W24[j], h[j]);
    if constexpr (SKIP) {
        const float* __restrict__ W25 = W1 + 25 * 32;
#pragma unroll
        for (int j = 0; j < 32; ++j) h[j] = fmaf(attr, W25[j], h[j]);
    }
    float out = b2[0];
#pragma unroll
    for (int j = 0; j < 32; ++j) out = fmaf(fmaxf(h[j], 0.0f), W2[j], out);

    if (valid) {
        if constexpr (STORE) e_out[i] = out;
        if constexpr (VALS) {
            const u32 eid = (u32)(key >> 34);
            vals_out[eid] = (r == c) ? expf(out) : out;
        }
    }
    if constexpr (GAGG) {
        const float s = wave_sum(valid ? out : 0.0f);
        if ((t & 63) == 0) wpart[t >> 6] = s;
        __syncthreads();
        if (t == 0)
            atomicAdd(&ebins[lid & 63],
                      wpart[0] + wpart[1] + wpart[2] + wpart[3]);
    }
}

// -- per-node MLP: CSR segment sum + MLP; EVEN also fuses the upper Atab --
// (l_n is in registers as o[8]; AtabU[n] = l_n . W1_next[8:16])

template <bool EVEN>
__global__ __launch_bounds__(256) void nodemlp_kernel(
    const float* __restrict__ ep,      // row-sorted edge embeddings
    const u32* __restrict__ row_offs,  // N+1 CSR offsets
    const float4* __restrict__ xf,   // node features: x (lower) or l_n (upper)
    const float* __restrict__ g,     // gslot[j] (materialized)
    const float* __restrict__ nW1, const float* __restrict__ nb1,
    const float* __restrict__ nW2, const float* __restrict__ nb2,
    float* __restrict__ n_out,         // l_n (8N) if EVEN
    float* __restrict__ nbins,         // 64 x 16 n-mean partial bins
    const float* __restrict__ W1u,     // next (upper) edge W1 slice, if EVEN
    float4* __restrict__ AtabU,        // upper A-table out, if EVEN
    int N, int cpn) {
    __shared__ float biasN[32];
    __shared__ float npart[4][8];
    const int t = threadIdx.x;
    if (t < 32) {
        float v = nb1[t];
#pragma unroll
        for (int k = 0; k < 8; ++k) v = fmaf(g[k], nW1[k * 32 + t], v);
        biasN[t] = v;
    }
    __syncthreads();
    const int lid = (blockIdx.x & 7) * cpn + (blockIdx.x >> 3);
    const int n = lid * 256 + t;
    const bool active = n < N;
    const int idx = active ? n : (N - 1);
    const u32 beg = row_offs[idx], end = row_offs[idx + 1];
    float ssum = 0.0f;
    for (u32 i = beg; i < end; ++i) ssum += ep[i];
    const float agg = ssum / fmaxf((float)(end - beg), 1.0f);
    const float4 x0 = xf[2 * (size_t)idx], x1 = xf[2 * (size_t)idx + 1];
    float in[9] = {x0.x, x0.y, x0.z, x0.w, x1.x, x1.y, x1.z, x1.w, agg};
    float h[32];
#pragma unroll
    for (int j = 0; j < 8; ++j) {
        const float4 bb = reinterpret_cast<const float4*>(biasN)[j];
        h[4 * j + 0] = bb.x; h[4 * j + 1] = bb.y;
        h[4 * j + 2] = bb.z; h[4 * j + 3] = bb.w;
    }
    const float* __restrict__ Wk = nW1 + 8 * 32;
#pragma unroll
    for (int k = 0; k < 9; ++k) {
        const float v = in[k];
#pragma unroll
        for (int j = 0; j < 32; ++j) h[j] = fmaf(v, Wk[k * 32 + j], h[j]);
    }
    float o[8];
#pragma unroll
    for (int q = 0; q < 8; ++q) o[q] = nb2[q];
#pragma unroll
    for (int j = 0; j < 32; ++j) {
        const float hv = fmaxf(h[j], 0.0f);
#pragma unroll
        for (int q = 0; q < 8; ++q) o[q] = fmaf(hv, nW2[j * 8 + q], o[q]);
    }
    if constexpr (EVEN) {
        if (active) {
            reinterpret_cast<float4*>(n_out)[2 * n] =
                make_float4(o[0], o[1], o[2], o[3]);
            reinterpret_cast<float4*>(n_out)[2 * n + 1] =
                make_float4(o[4], o[5], o[6], o[7]);
            // fused upper A-table: a = l_n . W1u[8:16]
            const float* __restrict__ WA = W1u + 8 * 32;
            float a[32];
#pragma unroll
            for (int j = 0; j < 32; ++j) a[j] = 0.0f;
#pragma unroll
            for (int k = 0; k < 8; ++k) {
                const float v = o[k];
#pragma unroll
                for (int j = 0; j < 32; ++j)
                    a[j] = fmaf(v, WA[k * 32 + j], a[j]);
            }
            float4* An = AtabU + 8 * (size_t)n;
#pragma unroll
            for (int q = 0; q < 8; ++q)
                An[q] = make_float4(a[4 * q], a[4 * q + 1], a[4 * q + 2],
                                    a[4 * q + 3]);
        }
    }
#pragma unroll
    for (int q = 0; q < 8; ++q) {
        const float s2 = wave_sum(active ? o[q] : 0.0f);
        if ((t & 63) == 0) npart[t >> 6][q] = s2;
    }
    __syncthreads();
    if (t < 8) {
        float a = 0.0f;
#pragma unroll
        for (int w = 0; w < 4; ++w) a += npart[w][t];
        atomicAdd(&nbins[(blockIdx.x & 63) * 16 + t], a);
    }
}

extern "C" void kernel_launch(void* const* d_in, const int* in_sizes, int n_in,
                              void* d_out, int out_size, void* d_ws,
                              size_t ws_size, hipStream_t stream) {
    const float* x = (const float*)d_in[0];
    const int* l_ei = (const int*)d_in[1];
    const int* u_ei = (const int*)d_in[2];
    const float* l_attr = (const float*)d_in[3];
    const float* u_attr = (const float*)d_in[4];
    const float* eW1 = (const float*)d_in[5];
    const float* eb1 = (const float*)d_in[6];
    const float* eW2 = (const float*)d_in[7];
    const float* eb2 = (const float*)d_in[8];
    const float* nW1 = (const float*)d_in[9];
    const float* nb1 = (const float*)d_in[10];
    const float* nW2 = (const float*)d_in[11];
    const float* nb2 = (const float*)d_in[12];
    const float* gW1 = (const float*)d_in[13];
    const float* gb1 = (const float*)d_in[14];
    const float* gW2 = (const float*)d_in[15];
    const float* gb2 = (const float*)d_in[16];

    const int E = in_sizes[3];      // 1,100,000
    const int N = in_sizes[0] / 8;  // 100,000
    const int B = (N + NB_SIZE - 1) >> NB_SHIFT;  // 391 buckets
    const int Ep = (E + 3) & ~3;    // float4-safe stride for emb arrays

    // workspace layout (~101MB, ws = 256MB):
    //  [ekeys 2E u64][eattrs 2E f32]
    //  [tmp 2E uint4 (dead after sort) -> AtabU 32N + l_e + u_e + l_n]
    //  [AtabL 96N][small region]
    u64* ekeys = (u64*)d_ws;                       // 2E keys
    float* eattrs = (float*)(ekeys + (size_t)2 * E);  // 2E attrs
    uint4* tmp = (uint4*)(eattrs + (size_t)2 * E); // 2E tmp records
    float* AtabU = (float*)tmp;                    // 32N (alias, post-sort)
    float* l_e = AtabU + (size_t)32 * N;           // Ep (alias)
    float* u_e = l_e + Ep;                         // Ep (alias)
    float* l_n = u_e + Ep;                         // 8N (alias; fits in tmp)
    float* AtabL = (float*)(tmp + (size_t)2 * E);  // 96N (3 lower tables)
    float* gslot = AtabL + (size_t)96 * N;         // 7 x 8
    u32* hist = (u32*)(gslot + 56);                // 2B
    float* dyn_all = (float*)(hist + 2 * B);       // 5 * RSTRIDE (+1 pad)
    u32* offs = (u32*)(dyn_all + 6 * RSTRIDE);     // 2(B+1)
    u32* cur = offs + 2 * (B + 1);                 // 2B
    u32* row_offs = cur + 2 * B;                   // 2(N+1) CSR offsets

    const int* lr = l_ei;
    const int* lc = l_ei + E;
    const int* ur = u_ei;
    const int* uc = u_ei + E;
    const int sg = (E + SCHUNK - 1) / SCHUNK;
    const int ng = (N + 255) / 256;
    const int ngp = (ng + 7) & ~7;   // padded node grid (%8) for XCD swizzle
    const int cpn = ngp >> 3;
    const int eg = (E + 255) / 256;
    const int nwg8 = (eg + 7) & ~7;  // padded edge grid (%8)
    const int cpx = nwg8 >> 3;
    const float invE = 1.0f / (float)E;
    float* outL = (float*)d_out;
    float* outU = outL + E;

    // one memset: gslots + hist + all 6 bin regions
    hipMemsetAsync(gslot, 0, (size_t)(56 + 2 * B + 6 * RSTRIDE) * sizeof(float),
                   stream);
    hist_kernel<<<dim3(64, 2), 512, 0, stream>>>(lr, ur, hist, E, B);
    scan_kernel<<<1, 512, 0, stream>>>(hist, offs, cur, B);
    // dual-segment scatter + sort (blockIdx.y = segment); sort also fuses
    // the 3 lower A-tables (segment-0 blocks).
    scatter_kernel<<<dim3(sg, 2), 512, 0, stream>>>(lr, lc, ur, uc, l_attr,
                                                    u_attr, cur, tmp, E, B);
    sort_kernel<<<dim3(B, 2), 512, 0, stream>>>(tmp, ekeys, eattrs, offs,
                                                row_offs, (const float4*)x,
                                                eW1, (float4*)AtabL, E, N, B);

    // weight-slice per GraphNet j: lower i -> i, upper i -> 3+i
    const size_t wsl[6] = {0, 3, 1, 4, 2, 5};

    for (int j = 0; j < 6; ++j) {
        const bool lower = !(j & 1);
        const size_t sl = wsl[j];
        float* ebins = dyn_all + (size_t)j * RSTRIDE;  // j=5 region unused
        float* nbins = ebins + 64;
        const float* pe = (j >= 1) ? dyn_all + (size_t)(j - 1) * RSTRIDE : nullptr;
        const float* pn = (j >= 1) ? pe + 64 : nullptr;
        const size_t psl = (j >= 1) ? wsl[j - 1] : 0;
        const float4* exf = (const float4*)(lower ? x : l_n);
        const u64* ekey_t = ekeys + (size_t)(lower ? 0 : 1) * E;
        const float* eattr_t = eattrs + (size_t)(lower ? 0 : 1) * E;
        const u32* roffs = row_offs + (size_t)(lower ? 0 : 1) * (N + 1);
        const float* eprev = lower ? l_e : u_e;  // unused when FIRST
        float* e_out = lower ? l_e : u_e;
        const float* gprev = gslot + (size_t)(j >= 1 ? j - 1 : 0) * 8;
        float* gout = gslot + (size_t)j * 8;
        const float* Atab_j =
            lower ? AtabL + (size_t)(j >> 1) * 32 * N : AtabU;

#define EDGE_ARGS                                                             \
    ekey_t, eattr_t, (const float4*)Atab_j, exf, eprev, eW1 + sl * 832,       \
        eb1 + sl * 32, eW2 + sl * 32, eb2 + sl, gprev, gout, pe, pn,          \
        gW1 + psl * 544, gb1 + psl * 32, gW2 + psl * 256, gb2 + psl * 8,      \
        ebins, e_out, (j == 4) ? outL : outU, E, N, invE, cpx

        switch (j) {  // SKIP, FIRST, GAGG, VALS, STORE, GCOMP
            case 0: edge_kernel<false, true, true, false, true, false>
                        <<<nwg8, 256, 0, stream>>>(EDGE_ARGS); break;
            case 1: edge_kernel<false, true, true, false, true, true>
                        <<<nwg8, 256, 0, stream>>>(EDGE_ARGS); break;
            case 2: edge_kernel<true, false, true, false, true, true>
                        <<<nwg8, 256, 0, stream>>>(EDGE_ARGS); break;
            case 3: edge_kernel<false, false, true, false, true, true>
                        <<<nwg8, 256, 0, stream>>>(EDGE_ARGS); break;
            case 4: edge_kernel<true, false, true, true, true, true>
                        <<<nwg8, 256, 0, stream>>>(EDGE_ARGS); break;
            case 5: edge_kernel<false, false, false, true, false, true>
                        <<<nwg8, 256, 0, stream>>>(EDGE_ARGS); break;
        }
#undef EDGE_ARGS

        if (j == 5) break;  // final upper GraphNet: edge output only

#define NODE_ARGS                                                             \
    e_out, roffs, exf, gslot + (size_t)j * 8, nW1 + sl * 544, nb1 + sl * 32,  \
        nW2 + sl * 256, nb2 + sl * 8, l_n, nbins,                             \
        eW1 + wsl[j + 1] * 832, (float4*)AtabU, N, cpn

        switch (j) {  // EVEN (store l_n + fused upper Atab)
            case 0: nodemlp_kernel<true>
                        <<<ngp, 256, 0, stream>>>(NODE_ARGS); break;
            case 1: nodemlp_kernel<false>
                        <<<ngp, 256, 0, stream>>>(NODE_ARGS); break;
            case 2: nodemlp_kernel<true>
                        <<<ngp, 256, 0, stream>>>(NODE_ARGS); break;
            case 3: nodemlp_kernel<false>
                        <<<ngp, 256, 0, stream>>>(NODE_ARGS); break;
            case 4: nodemlp_kernel<true>
                        <<<ngp, 256, 0, stream>>>(NODE_ARGS); break;
        }
#undef NODE_ARGS
    }
}

// Round 17
// 492.757 us; speedup vs baseline: 3.5324x; 1.0393x over previous
//
#include <hip/hip_runtime.h>

// NeuralIF GraphNet: 3 layers x (lower GraphNet, upper GraphNet).
// FINAL (R25) = R20 exactly, the best measured configuration: 489.9us.
// Journey: 548 (R7 baseline) -> 508.9 (R14 row-sort + CSR nodemlp) ->
//          503.6 (R19 nodew elimination) -> 489.9 (R20 dual-segment prep).
// Established dead ends (two strikes each):
//  - per-thread ILP (R16/R18): regalloc caps VGPR at 48 and spills h[32]
//    pairs regardless of __launch_bounds__; 2 edges/thread untestable.
//  - grid-wide fusion (R21 cooperative launch rejected under graph capture;
//    R23 manual barrier ~100us/barrier across 8 non-coherent L2s).
//  - folding work into small-grid tail-bound kernels (R10 LDS window,
//    R24 atabx-in-sort): extends critical path instead of hiding.
// Measured neutral: einfo diet (R15), XCD producer-consumer swizzle (R17).
// Residual profile: ~250us gather-latency-bound edge MLPs, ~95us prep
// (scatter write-amp on scattered 16B records), ~45us nodemlp, ~80us
// launch gaps (cheaper than any barrier alternative on this platform).

typedef unsigned int u32;
typedef unsigned long long u64;

#define NB_SHIFT 8
#define NB_SIZE 256
#define RSTRIDE 1104  // per-GraphNet region: ebins[64] nbins[64*16] pad

__device__ __forceinline__ float wave_sum(float v) {
#pragma unroll
    for (int off = 32; off > 0; off >>= 1) v += __shfl_down(v, off, 64);
    return v;
}

// ---------------- bucketed-list build (once per call) ----------------

__global__ __launch_bounds__(512) void hist_kernel(
    const int* __restrict__ lr, const int* __restrict__ ur,
    u32* __restrict__ hist, int E, int B) {
    __shared__ u32 h[512];
    const int t = threadIdx.x;
    if (t < B) h[t] = 0;
    __syncthreads();
    const int s = blockIdx.y;
    const int* rows = s ? ur : lr;
    for (int i = blockIdx.x * 512 + t; i < E; i += gridDim.x * 512)
        atomicAdd(&h[rows[i] >> NB_SHIFT], 1u);
    __syncthreads();
    if (t < B && h[t]) atomicAdd(&hist[s * B + t], h[t]);
}

// parallel exclusive scan of both segments (B <= 512), one block
__global__ __launch_bounds__(512) void scan_kernel(
    const u32* __restrict__ hist, u32* __restrict__ offs,
    u32* __restrict__ cur, int B) {
    __shared__ u32 sh[512];
    const int t = threadIdx.x;
    for (int s = 0; s < 2; ++s) {
        const u32 v = (t < B) ? hist[s * B + t] : 0u;
        sh[t] = v;
        __syncthreads();
#pragma unroll
        for (int off = 1; off < 512; off <<= 1) {
            const u32 add = (t >= off) ? sh[t - off] : 0u;
            __syncthreads();
            sh[t] += add;
            __syncthreads();
        }
        const u32 exc = sh[t] - v;
        if (t < B) {
            offs[s * (B + 1) + t] = exc;
            cur[s * B + t] = exc;
        }
        if (t == 511) offs[s * (B + 1) + B] = sh[511];
        __syncthreads();
    }
}

// dual-segment scatter: packed bucket-permuted records {row, col, eid, attr}
#define SCHUNK 4096
__global__ __launch_bounds__(512) void scatter_kernel(
    const int* __restrict__ lr, const int* __restrict__ lc,
    const int* __restrict__ ur, const int* __restrict__ uc,
    const float* __restrict__ la, const float* __restrict__ ua,
    u32* __restrict__ cur, uint4* __restrict__ tmp, int E, int B) {
    __shared__ u32 lcnt[512], lbase[512];
    const int t = threadIdx.x;
    const int s = blockIdx.y;
    const int* rows = s ? ur : lr;
    const int* cols = s ? uc : lc;
    const float* attr = s ? ua : la;
    uint4* my = tmp + (size_t)s * E;
    if (t < B) lcnt[t] = 0;
    __syncthreads();
    const int base_e = blockIdx.x * SCHUNK;
#pragma unroll
    for (int k = 0; k < SCHUNK / 512; ++k) {
        const int e = base_e + k * 512 + t;
        if (e < E) atomicAdd(&lcnt[rows[e] >> NB_SHIFT], 1u);
    }
    __syncthreads();
    if (t < B) {
        const u32 c = lcnt[t];
        lbase[t] = c ? atomicAdd(&cur[s * B + t], c) : 0u;
        lcnt[t] = 0;
    }
    __syncthreads();
#pragma unroll
    for (int k = 0; k < SCHUNK / 512; ++k) {
        const int e = base_e + k * 512 + t;
        if (e < E) {
            const int r = rows[e];
            const int b = r >> NB_SHIFT;
            const u32 pos = lbase[b] + atomicAdd(&lcnt[b], 1u);
            my[pos] = make_uint4((u32)r, (u32)cols[e], (u32)e,
                                 __float_as_uint(attr[e]));
        }
    }
}

// ---- dual-segment per-bucket LDS counting sort: bucket -> row order ----
// Emits split arrays: u64 key {eid:21|row:17|col:17} + float attr.
// Also emits per-node CSR offsets (row_offs). One block per (bucket,segment).

__global__ __launch_bounds__(512) void sort_kernel(
    const uint4* __restrict__ tmp, u64* __restrict__ ekeys,
    float* __restrict__ eattrs, const u32* __restrict__ offs,
    u32* __restrict__ row_offs, int E, int N, int B) {
    __shared__ u32 cnt[NB_SIZE];
    __shared__ u32 scn[NB_SIZE];
    const int t = threadIdx.x;
    const int s = blockIdx.y;
    const int b = blockIdx.x;
    const uint4* in = tmp + (size_t)s * E;
    u64* okey = ekeys + (size_t)s * E;
    float* oattr = eattrs + (size_t)s * E;
    u32* rofs = row_offs + (size_t)s * (N + 1);
    const u32 beg = offs[s * (B + 1) + b], end = offs[s * (B + 1) + b + 1];
    if (t < NB_SIZE) cnt[t] = 0;
    __syncthreads();
    for (u32 i = beg + t; i < end; i += 512)
        atomicAdd(&cnt[in[i].x & (NB_SIZE - 1)], 1u);
    __syncthreads();
    if (t < NB_SIZE) scn[t] = cnt[t];
    __syncthreads();
#pragma unroll
    for (int off = 1; off < NB_SIZE; off <<= 1) {
        u32 add = 0;
        if (t < NB_SIZE && t >= off) add = scn[t - off];
        __syncthreads();
        if (t < NB_SIZE) scn[t] += add;
        __syncthreads();
    }
    const int n0 = b << NB_SHIFT;
    if (t < NB_SIZE) {
        const u32 excl = scn[t] - cnt[t];
        if (n0 + t < N) rofs[n0 + t] = beg + excl;
        cnt[t] = excl;  // reuse as write cursor
    }
    if (b == 0 && t == 0) rofs[N] = (u32)E;
    __syncthreads();
    for (u32 i = beg + t; i < end; i += 512) {
        const uint4 r = in[i];
        const u32 pos = beg + atomicAdd(&cnt[r.x & (NB_SIZE - 1)], 1u);
        okey[pos] = ((u64)r.z << 34) | ((u64)(r.x & 0x1FFFFu) << 17) |
                    (u64)(r.y & 0x1FFFFu);
        oattr[pos] = __uint_as_float(r.w);
    }
}

// ---- upfront: all 3 lower A-tables from static x (g-independent) ----
// AtabL[m][n][j] = sum_k x[n,k] * W1_m[(8+k)*32+j], m = lower slice 0,1,2

__global__ __launch_bounds__(256) void atabx_kernel(
    const float4* __restrict__ xf, const float* __restrict__ eW1,
    float4* __restrict__ AtabL, int N) {
    const int n = blockIdx.x * 256 + threadIdx.x;
    if (n >= N) return;
    const float4 x0 = xf[2 * (size_t)n], x1 = xf[2 * (size_t)n + 1];
    const float xs[8] = {x0.x, x0.y, x0.z, x0.w, x1.x, x1.y, x1.z, x1.w};
    for (int m = 0; m < 3; ++m) {
        const float* __restrict__ WA = eW1 + (size_t)m * 832 + 8 * 32;
        float a[32];
#pragma unroll
        for (int j = 0; j < 32; ++j) a[j] = 0.0f;
#pragma unroll
        for (int k = 0; k < 8; ++k) {
            const float v = xs[k];
#pragma unroll
            for (int j = 0; j < 32; ++j) a[j] = fmaf(v, WA[k * 32 + j], a[j]);
        }
        float4* An = AtabL + (size_t)m * 8 * N + 8 * (size_t)n;
#pragma unroll
        for (int q = 0; q < 8; ++q)
            An[q] = make_float4(a[4 * q], a[4 * q + 1], a[4 * q + 2],
                                a[4 * q + 3]);
    }
}

// ---------------- edge MLP: flat grid, one edge per thread ----------------
// GCOMP (wave 0) computes g inline from prev bins; t<32 folds b1 + g.W1[0:8]
// into LDS biasE. Atab rows carry only x.W1[8:16]. Row-sorted order keeps
// A-row gathers L1-broadcast; XCD-chunked swizzle.

template <bool SKIP, bool FIRST, bool GAGG, bool VALS, bool STORE, bool GCOMP>
__global__ __launch_bounds__(256) void edge_kernel(
    const u64* __restrict__ ekey,      // packed row-sorted keys
    const float* __restrict__ eattr,   // permuted original attrs
    const float4* __restrict__ Atab,   // per-node x.W1[8:16] partials
    const float4* __restrict__ xf,     // current node features (x or l_n)
    const float* __restrict__ eprev,   // prev edge emb (permuted), !FIRST
    const float* __restrict__ W1,      // 26x32 slice (row-major k,j)
    const float* __restrict__ b1,      // 32
    const float* __restrict__ W2,      // 32
    const float* __restrict__ b2,      // 1
    const float* __restrict__ gprev,   // gslot[j-1] (or gslot[0]=0)
    float* __restrict__ gout,          // gslot[j] (GCOMP: block0 writes)
    const float* __restrict__ pebins,  // prev region e-mean bins (GCOMP)
    const float* __restrict__ pnbins,  // prev region n-mean bins (GCOMP)
    const float* __restrict__ gW1, const float* __restrict__ gb1,
    const float* __restrict__ gW2, const float* __restrict__ gb2,
    float* __restrict__ ebins,         // this region's e-mean bins (GAGG)
    float* __restrict__ e_out,         // edge emb store (permuted, STORE)
    float* __restrict__ vals_out,      // final output segment (VALS)
    int E, int N, float inv_E, int cpx) {
    __shared__ float gsh[8];
    __shared__ float biasE[32];
    __shared__ float wpart[4];
    const int t = threadIdx.x;
    const int lid = (blockIdx.x & 7) * cpx + (blockIdx.x >> 3);
    const int i0 = lid * 256;
    if (i0 >= E) return;  // padded-grid tail block (uniform exit)

    if constexpr (GCOMP) {
        if (t < 64) {  // wave 0: g = gMLP(n_mean, e_mean, g_prev)
            float nb[8];
#pragma unroll
            for (int q = 0; q < 8; ++q) nb[q] = pnbins[t * 16 + q];
            const float eb = pebins[t];
            float gin[17];
#pragma unroll
            for (int q = 0; q < 8; ++q) {
                const float s = wave_sum(nb[q]);
                gin[q] = __shfl(s, 0, 64) / (float)N;
            }
            const float es = wave_sum(eb);
            gin[8] = __shfl(es, 0, 64) * inv_E;
#pragma unroll
            for (int k = 0; k < 8; ++k) gin[9 + k] = gprev[k];
            float hv = 0.0f;
            if (t < 32) {
                hv = gb1[t];
#pragma unroll
                for (int k = 0; k < 17; ++k)
                    hv = fmaf(gin[k], gW1[k * 32 + t], hv);
                hv = fmaxf(hv, 0.0f);
            }
#pragma unroll
            for (int q = 0; q < 8; ++q) {
                const float c = (t < 32) ? hv * gW2[t * 8 + q] : 0.0f;
                const float s = wave_sum(c);
                if (t == 0) {
                    const float gv = gb2[q] + s;
                    gsh[q] = gv;
                    if (blockIdx.x == 0) gout[q] = gv;
                }
            }
        }
    } else {
        if (t < 8) gsh[t] = gprev[t];  // zeros for GraphNet 0
    }
    __syncthreads();
    if (t < 32) {  // fold uniform global contribution + b1 into bias
        float v = b1[t];
#pragma unroll
        for (int k = 0; k < 8; ++k) v = fmaf(gsh[k], W1[k * 32 + t], v);
        biasE[t] = v;
    }
    __syncthreads();

    const int i = i0 + t;
    const bool valid = i < E;
    const int idx = valid ? i : i0;

    const u64 key = ekey[idx];
    const u32 c = (u32)key & 0x1FFFFu;
    const u32 r = (u32)(key >> 17) & 0x1FFFFu;
    float attr = 0.0f;
    if constexpr (FIRST || SKIP) attr = eattr[idx];
    float epv;
    if constexpr (FIRST) epv = attr;
    else epv = eprev[idx];
    // A-row gather (8x16B; consecutive lanes share rows -> broadcast)
    const float4* __restrict__ Ar = Atab + 8 * (size_t)r;
    float h[32];
#pragma unroll
    for (int q = 0; q < 8; ++q) {
        const float4 av = Ar[q];
        const float4 bi = reinterpret_cast<const float4*>(biasE)[q];
        h[4 * q + 0] = bi.x + av.x; h[4 * q + 1] = bi.y + av.y;
        h[4 * q + 2] = bi.z + av.z; h[4 * q + 3] = bi.w + av.w;
    }
    // col features (32B gather, L2-resident table)
    const float4 xc0 = xf[2 * (size_t)c], xc1 = xf[2 * (size_t)c + 1];
    const float cx[8] = {xc0.x, xc0.y, xc0.z, xc0.w,
                         xc1.x, xc1.y, xc1.z, xc1.w};
    const float* __restrict__ Wc = W1 + 16 * 32;  // col rows 16..23
#pragma unroll
    for (int k = 0; k < 8; ++k) {
        const float v = cx[k];
#pragma unroll
        for (int j = 0; j < 32; ++j) h[j] = fmaf(v, Wc[k * 32 + j], h[j]);
    }
    const float* __restrict__ W24 = W1 + 24 * 32;
#pragma unroll
    for (int j = 0; j < 32; ++j) h[j] = fmaf(epv, W24[j], h[j]);
    if constexpr (SKIP) {
        const float* __restrict__ W25 = W1 + 25 * 32;
#pragma unroll
        for (int j = 0; j < 32; ++j) h[j] = fmaf(attr, W25[j], h[j]);
    }
    float out = b2[0];
#pragma unroll
    for (int j = 0; j < 32; ++j) out = fmaf(fmaxf(h[j], 0.0f), W2[j], out);

    if (valid) {
        if constexpr (STORE) e_out[i] = out;
        if constexpr (VALS) {
            const u32 eid = (u32)(key >> 34);
            vals_out[eid] = (r == c) ? expf(out) : out;
        }
    }
    if constexpr (GAGG) {
        const float s = wave_sum(valid ? out : 0.0f);
        if ((t & 63) == 0) wpart[t >> 6] = s;
        __syncthreads();
        if (t == 0)
            atomicAdd(&ebins[lid & 63],
                      wpart[0] + wpart[1] + wpart[2] + wpart[3]);
    }
}

// -- per-node MLP: CSR segment sum + MLP; EVEN also fuses the upper Atab --
// (l_n is in registers as o[8]; AtabU[n] = l_n . W1_next[8:16])

template <bool EVEN>
__global__ __launch_bounds__(256) void nodemlp_kernel(
    const float* __restrict__ ep,      // row-sorted edge embeddings
    const u32* __restrict__ row_offs,  // N+1 CSR offsets
    const float4* __restrict__ xf,   // node features: x (lower) or l_n (upper)
    const float* __restrict__ g,     // gslot[j] (materialized)
    const float* __restrict__ nW1, const float* __restrict__ nb1,
    const float* __restrict__ nW2, const float* __restrict__ nb2,
    float* __restrict__ n_out,         // l_n (8N) if EVEN
    float* __restrict__ nbins,         // 64 x 16 n-mean partial bins
    const float* __restrict__ W1u,     // next (upper) edge W1 slice, if EVEN
    float4* __restrict__ AtabU,        // upper A-table out, if EVEN
    int N, int cpn) {
    __shared__ float biasN[32];
    __shared__ float npart[4][8];
    const int t = threadIdx.x;
    if (t < 32) {
        float v = nb1[t];
#pragma unroll
        for (int k = 0; k < 8; ++k) v = fmaf(g[k], nW1[k * 32 + t], v);
        biasN[t] = v;
    }
    __syncthreads();
    const int lid = (blockIdx.x & 7) * cpn + (blockIdx.x >> 3);
    const int n = lid * 256 + t;
    const bool active = n < N;
    const int idx = active ? n : (N - 1);
    const u32 beg = row_offs[idx], end = row_offs[idx + 1];
    float ssum = 0.0f;
    for (u32 i = beg; i < end; ++i) ssum += ep[i];
    const float agg = ssum / fmaxf((float)(end - beg), 1.0f);
    const float4 x0 = xf[2 * (size_t)idx], x1 = xf[2 * (size_t)idx + 1];
    float in[9] = {x0.x, x0.y, x0.z, x0.w, x1.x, x1.y, x1.z, x1.w, agg};
    float h[32];
#pragma unroll
    for (int j = 0; j < 8; ++j) {
        const float4 bb = reinterpret_cast<const float4*>(biasN)[j];
        h[4 * j + 0] = bb.x; h[4 * j + 1] = bb.y;
        h[4 * j + 2] = bb.z; h[4 * j + 3] = bb.w;
    }
    const float* __restrict__ Wk = nW1 + 8 * 32;
#pragma unroll
    for (int k = 0; k < 9; ++k) {
        const float v = in[k];
#pragma unroll
        for (int j = 0; j < 32; ++j) h[j] = fmaf(v, Wk[k * 32 + j], h[j]);
    }
    float o[8];
#pragma unroll
    for (int q = 0; q < 8; ++q) o[q] = nb2[q];
#pragma unroll
    for (int j = 0; j < 32; ++j) {
        const float hv = fmaxf(h[j], 0.0f);
#pragma unroll
        for (int q = 0; q < 8; ++q) o[q] = fmaf(hv, nW2[j * 8 + q], o[q]);
    }
    if constexpr (EVEN) {
        if (active) {
            reinterpret_cast<float4*>(n_out)[2 * n] =
                make_float4(o[0], o[1], o[2], o[3]);
            reinterpret_cast<float4*>(n_out)[2 * n + 1] =
                make_float4(o[4], o[5], o[6], o[7]);
            // fused upper A-table: a = l_n . W1u[8:16]
            const float* __restrict__ WA = W1u + 8 * 32;
            float a[32];
#pragma unroll
            for (int j = 0; j < 32; ++j) a[j] = 0.0f;
#pragma unroll
            for (int k = 0; k < 8; ++k) {
                const float v = o[k];
#pragma unroll
                for (int j = 0; j < 32; ++j)
                    a[j] = fmaf(v, WA[k * 32 + j], a[j]);
            }
            float4* An = AtabU + 8 * (size_t)n;
#pragma unroll
            for (int q = 0; q < 8; ++q)
                An[q] = make_float4(a[4 * q], a[4 * q + 1], a[4 * q + 2],
                                    a[4 * q + 3]);
        }
    }
#pragma unroll
    for (int q = 0; q < 8; ++q) {
        const float s2 = wave_sum(active ? o[q] : 0.0f);
        if ((t & 63) == 0) npart[t >> 6][q] = s2;
    }
    __syncthreads();
    if (t < 8) {
        float a = 0.0f;
#pragma unroll
        for (int w = 0; w < 4; ++w) a += npart[w][t];
        atomicAdd(&nbins[(blockIdx.x & 63) * 16 + t], a);
    }
}

extern "C" void kernel_launch(void* const* d_in, const int* in_sizes, int n_in,
                              void* d_out, int out_size, void* d_ws,
                              size_t ws_size, hipStream_t stream) {
    const float* x = (const float*)d_in[0];
    const int* l_ei = (const int*)d_in[1];
    const int* u_ei = (const int*)d_in[2];
    const float* l_attr = (const float*)d_in[3];
    const float* u_attr = (const float*)d_in[4];
    const float* eW1 = (const float*)d_in[5];
    const float* eb1 = (const float*)d_in[6];
    const float* eW2 = (const float*)d_in[7];
    const float* eb2 = (const float*)d_in[8];
    const float* nW1 = (const float*)d_in[9];
    const float* nb1 = (const float*)d_in[10];
    const float* nW2 = (const float*)d_in[11];
    const float* nb2 = (const float*)d_in[12];
    const float* gW1 = (const float*)d_in[13];
    const float* gb1 = (const float*)d_in[14];
    const float* gW2 = (const float*)d_in[15];
    const float* gb2 = (const float*)d_in[16];

    const int E = in_sizes[3];      // 1,100,000
    const int N = in_sizes[0] / 8;  // 100,000
    const int B = (N + NB_SIZE - 1) >> NB_SHIFT;  // 391 buckets
    const int Ep = (E + 3) & ~3;    // float4-safe stride for emb arrays

    // workspace layout (~101MB, ws = 256MB):
    //  [ekeys 2E u64 17.6][eattrs 2E f32 8.8]
    //  [tmp 2E uint4 35.2 (dead after sort) -> AtabU 12.8 + l_e + u_e + l_n]
    //  [AtabL 96N 38.4][small region]
    u64* ekeys = (u64*)d_ws;                       // 2E keys
    float* eattrs = (float*)(ekeys + (size_t)2 * E);  // 2E attrs
    uint4* tmp = (uint4*)(eattrs + (size_t)2 * E); // 2E tmp records
    float* AtabU = (float*)tmp;                    // 32N (alias, post-sort)
    float* l_e = AtabU + (size_t)32 * N;           // Ep (alias)
    float* u_e = l_e + Ep;                         // Ep (alias)
    float* l_n = u_e + Ep;                         // 8N (alias; fits in tmp)
    float* AtabL = (float*)(tmp + (size_t)2 * E);  // 96N (3 lower tables)
    float* gslot = AtabL + (size_t)96 * N;         // 7 x 8
    u32* hist = (u32*)(gslot + 56);                // 2B
    float* dyn_all = (float*)(hist + 2 * B);       // 6 * RSTRIDE
    u32* offs = (u32*)(dyn_all + 6 * RSTRIDE);     // 2(B+1)
    u32* cur = offs + 2 * (B + 1);                 // 2B
    u32* row_offs = cur + 2 * B;                   // 2(N+1) CSR offsets

    const int* lr = l_ei;
    const int* lc = l_ei + E;
    const int* ur = u_ei;
    const int* uc = u_ei + E;
    const int sg = (E + SCHUNK - 1) / SCHUNK;
    const int ng = (N + 255) / 256;
    const int ngp = (ng + 7) & ~7;   // padded node grid (%8) for XCD swizzle
    const int cpn = ngp >> 3;
    const int eg = (E + 255) / 256;
    const int nwg8 = (eg + 7) & ~7;  // padded edge grid (%8)
    const int cpx = nwg8 >> 3;
    const float invE = 1.0f / (float)E;
    float* outL = (float*)d_out;
    float* outU = outL + E;

    // one memset: gslots + hist + all bin regions
    hipMemsetAsync(gslot, 0, (size_t)(56 + 2 * B + 6 * RSTRIDE) * sizeof(float),
                   stream);
    hist_kernel<<<dim3(64, 2), 512, 0, stream>>>(lr, ur, hist, E, B);
    scan_kernel<<<1, 512, 0, stream>>>(hist, offs, cur, B);
    // dual-segment scatter + sort (blockIdx.y = segment): full machine fill
    scatter_kernel<<<dim3(sg, 2), 512, 0, stream>>>(lr, lc, ur, uc, l_attr,
                                                    u_attr, cur, tmp, E, B);
    sort_kernel<<<dim3(B, 2), 512, 0, stream>>>(tmp, ekeys, eattrs, offs,
                                                row_offs, E, N, B);
    // all 3 lower A-tables (x is static; g lives in edge biasE)
    atabx_kernel<<<ng, 256, 0, stream>>>((const float4*)x, eW1,
                                         (float4*)AtabL, N);

    // weight-slice per GraphNet j: lower i -> i, upper i -> 3+i
    const size_t wsl[6] = {0, 3, 1, 4, 2, 5};

    for (int j = 0; j < 6; ++j) {
        const bool lower = !(j & 1);
        const size_t sl = wsl[j];
        float* ebins = dyn_all + (size_t)j * RSTRIDE;  // j=5 region unused
        float* nbins = ebins + 64;
        const float* pe = (j >= 1) ? dyn_all + (size_t)(j - 1) * RSTRIDE : nullptr;
        const float* pn = (j >= 1) ? pe + 64 : nullptr;
        const size_t psl = (j >= 1) ? wsl[j - 1] : 0;
        const float4* exf = (const float4*)(lower ? x : l_n);
        const u64* ekey_t = ekeys + (size_t)(lower ? 0 : 1) * E;
        const float* eattr_t = eattrs + (size_t)(lower ? 0 : 1) * E;
        const u32* roffs = row_offs + (size_t)(lower ? 0 : 1) * (N + 1);
        const float* eprev = lower ? l_e : u_e;  // unused when FIRST
        float* e_out = lower ? l_e : u_e;
        const float* gprev = gslot + (size_t)(j >= 1 ? j - 1 : 0) * 8;
        float* gout = gslot + (size_t)j * 8;
        const float* Atab_j =
            lower ? AtabL + (size_t)(j >> 1) * 32 * N : AtabU;

#define EDGE_ARGS                                                             \
    ekey_t, eattr_t, (const float4*)Atab_j, exf, eprev, eW1 + sl * 832,       \
        eb1 + sl * 32, eW2 + sl * 32, eb2 + sl, gprev, gout, pe, pn,          \
        gW1 + psl * 544, gb1 + psl * 32, gW2 + psl * 256, gb2 + psl * 8,      \
        ebins, e_out, (j == 4) ? outL : outU, E, N, invE, cpx

        switch (j) {  // SKIP, FIRST, GAGG, VALS, STORE, GCOMP
            case 0: edge_kernel<false, true, true, false, true, false>
                        <<<nwg8, 256, 0, stream>>>(EDGE_ARGS); break;
            case 1: edge_kernel<false, true, true, false, true, true>
                        <<<nwg8, 256, 0, stream>>>(EDGE_ARGS); break;
            case 2: edge_kernel<true, false, true, false, true, true>
                        <<<nwg8, 256, 0, stream>>>(EDGE_ARGS); break;
            case 3: edge_kernel<false, false, true, false, true, true>
                        <<<nwg8, 256, 0, stream>>>(EDGE_ARGS); break;
            case 4: edge_kernel<true, false, true, true, true, true>
                        <<<nwg8, 256, 0, stream>>>(EDGE_ARGS); break;
            case 5: edge_kernel<false, false, false, true, false, true>
                        <<<nwg8, 256, 0, stream>>>(EDGE_ARGS); break;
        }
#undef EDGE_ARGS

        if (j == 5) break;  // final upper GraphNet: edge output only

#define NODE_ARGS                                                             \
    e_out, roffs, exf, gslot + (size_t)j * 8, nW1 + sl * 544, nb1 + sl * 32,  \
        nW2 + sl * 256, nb2 + sl * 8, l_n, nbins,                             \
        eW1 + wsl[j + 1] * 832, (float4*)AtabU, N, cpn

        switch (j) {  // EVEN (store l_n + fused upper Atab)
            case 0: nodemlp_kernel<true>
                        <<<ngp, 256, 0, stream>>>(NODE_ARGS); break;
            case 1: nodemlp_kernel<false>
                        <<<ngp, 256, 0, stream>>>(NODE_ARGS); break;
            case 2: nodemlp_kernel<true>
                        <<<ngp, 256, 0, stream>>>(NODE_ARGS); break;
            case 3: nodemlp_kernel<false>
                        <<<ngp, 256, 0, stream>>>(NODE_ARGS); break;
            case 4: nodemlp_kernel<true>
                        <<<ngp, 256, 0, stream>>>(NODE_ARGS); break;
        }
#undef NODE_ARGS
    }
}